// Round 1
// baseline (595.102 us; speedup 1.0000x reference)
//
#include <hip/hip_runtime.h>

#define B_SZ    2
#define S_LEN   2048
#define D_MODEL 1024
#define H_NUM   16
#define DK_H    64
#define M_ROWS  (B_SZ * S_LEN)   // 4096

typedef __attribute__((ext_vector_type(8))) short  short8;
typedef __attribute__((ext_vector_type(4))) short  short4v;
typedef __attribute__((ext_vector_type(4))) float  floatx4;

// fp32 -> bf16 round-to-nearest-even (finite inputs only)
__device__ __forceinline__ short f2b(float f) {
    union { float f; unsigned u; } x; x.f = f;
    unsigned u = x.u + 0x7fffu + ((x.u >> 16) & 1u);
    return (short)(u >> 16);
}

// ---------------------------------------------------------------------------
// fp32 -> bf16 conversion, 4 elems/thread
// ---------------------------------------------------------------------------
__global__ void cvt_kernel(const float* __restrict__ in, short* __restrict__ out, int n) {
    int i = (blockIdx.x * 256 + threadIdx.x) * 4;
    if (i >= n) return;
    float4 v = *(const float4*)(in + i);
    short4v r;
    r[0] = f2b(v.x); r[1] = f2b(v.y); r[2] = f2b(v.z); r[3] = f2b(v.w);
    *(short4v*)(out + i) = r;
}

// ---------------------------------------------------------------------------
// QKV projection: C = (x @ W^T + b) * scale, written bf16 as [B,H,S,DK]
// NT GEMM: A [M,K] row-major, W [N,K] row-major. blockIdx.z picks q/k/v.
// Tile: workgroup 64(M)x64(N), wave = 16(M)x64(N), K-step 32.
// ---------------------------------------------------------------------------
__global__ __launch_bounds__(256)
void gemm_qkv_kernel(const short* __restrict__ xq, const short* __restrict__ xk,
                     const short* __restrict__ xv,
                     const short* __restrict__ wq, const short* __restrict__ wk,
                     const short* __restrict__ wv,
                     const float* __restrict__ bq, const float* __restrict__ bk,
                     const float* __restrict__ bv,
                     short* __restrict__ Qp, short* __restrict__ Kp, short* __restrict__ Vp)
{
    const int which = blockIdx.z;
    const short* A    = (which == 0) ? xq : (which == 1) ? xk : xv;
    const short* W    = (which == 0) ? wq : (which == 1) ? wk : wv;
    const float* bias = (which == 0) ? bq : (which == 1) ? bk : bv;
    short*       Out  = (which == 0) ? Qp : (which == 1) ? Kp : Vp;
    const float scale = (which == 0) ? 0.125f : 1.0f;   // 1/sqrt(64), exact in bf16

    const int wave = threadIdx.x >> 6, lane = threadIdx.x & 63;
    const int quad = lane >> 4, l16 = lane & 15;
    const int mrow  = blockIdx.x * 64 + wave * 16 + l16;  // A-frag row (m = lane&15)
    const int nbase = blockIdx.y * 64;

    floatx4 acc[4] = {{0,0,0,0},{0,0,0,0},{0,0,0,0},{0,0,0,0}};
    const short* Ap = A + (size_t)mrow * D_MODEL + quad * 8;

    for (int k0 = 0; k0 < D_MODEL; k0 += 32) {
        short8 a = *(const short8*)(Ap + k0);
#pragma unroll
        for (int nt = 0; nt < 4; ++nt) {
            short8 b = *(const short8*)(W + (size_t)(nbase + nt * 16 + l16) * D_MODEL + quad * 8 + k0);
            acc[nt] = __builtin_amdgcn_mfma_f32_16x16x32_bf16(a, b, acc[nt], 0, 0, 0);
        }
    }

    const int mtile = blockIdx.x * 64 + wave * 16;
#pragma unroll
    for (int nt = 0; nt < 4; ++nt) {
        int col = nbase + nt * 16 + l16;        // D col = lane&15
        int h = col >> 6, dk = col & 63;
        float bv_ = bias[col];
#pragma unroll
        for (int r = 0; r < 4; ++r) {
            int m = mtile + quad * 4 + r;       // D row = quad*4 + reg
            int bb = m >> 11, s = m & (S_LEN - 1);
            float v = (acc[nt][r] + bv_) * scale;
            Out[(((size_t)bb * H_NUM + h) * S_LEN + s) * DK_H + dk] = f2b(v);
        }
    }
}

// ---------------------------------------------------------------------------
// Flash-style causal attention. Grid: (S/64 q-tiles, B*H). 4 waves/block,
// each wave owns 16 q-rows. K tile + V^T tile in LDS (pad 8 shorts).
// ---------------------------------------------------------------------------
__global__ __launch_bounds__(256)
void attn_kernel(const short* __restrict__ Qp, const short* __restrict__ Kp,
                 const short* __restrict__ Vp, short* __restrict__ Xa)
{
    __shared__ short kt[64][72];      // [key][dk]
    __shared__ short vt[64][72];      // [dk][key]  (V transposed)
    __shared__ short pl[4][16][72];   // per-wave P round-trip

    const int bh = blockIdx.y;
    const int qt = blockIdx.x;
    const int wave = threadIdx.x >> 6, lane = threadIdx.x & 63;
    const int quad = lane >> 4, l16 = lane & 15;

    const short* Qb = Qp + (size_t)bh * S_LEN * DK_H;
    const short* Kb = Kp + (size_t)bh * S_LEN * DK_H;
    const short* Vb = Vp + (size_t)bh * S_LEN * DK_H;

    const int qrow_f = qt * 64 + wave * 16 + l16;           // A-frag q row
    short8 qf0 = *(const short8*)(Qb + (size_t)qrow_f * DK_H + quad * 8);
    short8 qf1 = *(const short8*)(Qb + (size_t)qrow_f * DK_H + 32 + quad * 8);

    floatx4 o[4] = {{0,0,0,0},{0,0,0,0},{0,0,0,0},{0,0,0,0}};
    float m_run[4] = {-1e30f, -1e30f, -1e30f, -1e30f};
    float l_run[4] = {0.f, 0.f, 0.f, 0.f};
    const int q0 = qt * 64 + wave * 16 + quad * 4;          // q row of reg r = q0+r

    for (int kti = 0; kti <= qt; ++kti) {
        const int kbase = kti * 64;
        __syncthreads();   // previous iter's LDS reads done before overwrite
        for (int c = threadIdx.x; c < 512; c += 256) {      // K tile: 64 rows x 4 chunks... 8 chunks
            int row = c >> 3, cc = c & 7;
            *(short8*)(&kt[row][cc * 8]) = *(const short8*)(Kb + (size_t)(kbase + row) * DK_H + cc * 8);
        }
        for (int c = threadIdx.x; c < 512; c += 256) {      // V tile, transposed into vt[dk][key]
            int row = c >> 3, cc = c & 7;
            union { short8 v; short e[8]; } u;
            u.v = *(const short8*)(Vb + (size_t)(kbase + row) * DK_H + cc * 8);
#pragma unroll
            for (int j = 0; j < 8; ++j) vt[cc * 8 + j][row] = u.e[j];
        }
        __syncthreads();

        // S = Q K^T  (Q pre-scaled by 1/8)
        floatx4 sc[4] = {{0,0,0,0},{0,0,0,0},{0,0,0,0},{0,0,0,0}};
#pragma unroll
        for (int nt = 0; nt < 4; ++nt) {
            short8 b0 = *(const short8*)(&kt[nt * 16 + l16][quad * 8]);
            sc[nt] = __builtin_amdgcn_mfma_f32_16x16x32_bf16(qf0, b0, sc[nt], 0, 0, 0);
            short8 b1 = *(const short8*)(&kt[nt * 16 + l16][32 + quad * 8]);
            sc[nt] = __builtin_amdgcn_mfma_f32_16x16x32_bf16(qf1, b1, sc[nt], 0, 0, 0);
        }

        if (kti == qt) {   // causal mask on diagonal tile
#pragma unroll
            for (int nt = 0; nt < 4; ++nt) {
                int key = kbase + nt * 16 + l16;
#pragma unroll
                for (int r = 0; r < 4; ++r)
                    if (key > q0 + r) sc[nt][r] = -1e30f;
            }
        }

        // online softmax; row r lives in the 16-lane group, butterfly over l16
        float alpha[4];
#pragma unroll
        for (int r = 0; r < 4; ++r) {
            float mx = fmaxf(fmaxf(sc[0][r], sc[1][r]), fmaxf(sc[2][r], sc[3][r]));
            mx = fmaxf(mx, __shfl_xor(mx, 1));
            mx = fmaxf(mx, __shfl_xor(mx, 2));
            mx = fmaxf(mx, __shfl_xor(mx, 4));
            mx = fmaxf(mx, __shfl_xor(mx, 8));
            float mnew = fmaxf(m_run[r], mx);
            float a = __expf(m_run[r] - mnew);
            float sum = 0.f;
#pragma unroll
            for (int nt = 0; nt < 4; ++nt) {
                float p = __expf(sc[nt][r] - mnew);
                sc[nt][r] = p;
                sum += p;
            }
            sum += __shfl_xor(sum, 1);
            sum += __shfl_xor(sum, 2);
            sum += __shfl_xor(sum, 4);
            sum += __shfl_xor(sum, 8);
            l_run[r] = l_run[r] * a + sum;
            m_run[r] = mnew;
            alpha[r] = a;
        }

        // P: C-layout regs -> LDS -> A-layout (m120-verified transform)
#pragma unroll
        for (int nt = 0; nt < 4; ++nt)
#pragma unroll
            for (int r = 0; r < 4; ++r)
                pl[wave][quad * 4 + r][nt * 16 + l16] = f2b(sc[nt][r]);
        __syncthreads();

#pragma unroll
        for (int nt = 0; nt < 4; ++nt)
#pragma unroll
            for (int r = 0; r < 4; ++r) o[nt][r] *= alpha[r];

#pragma unroll
        for (int ks = 0; ks < 2; ++ks) {
            short8 a = *(const short8*)(&pl[wave][l16][ks * 32 + quad * 8]);
#pragma unroll
            for (int nt = 0; nt < 4; ++nt) {
                short8 b = *(const short8*)(&vt[nt * 16 + l16][ks * 32 + quad * 8]);
                o[nt] = __builtin_amdgcn_mfma_f32_16x16x32_bf16(a, b, o[nt], 0, 0, 0);
            }
        }
    }

    // epilogue: O/l -> Xa in [B,S,D] so the output GEMM reads it row-major
    const int b_ = bh >> 4, h = bh & 15;
#pragma unroll
    for (int nt = 0; nt < 4; ++nt) {
        int col = h * 64 + nt * 16 + l16;
#pragma unroll
        for (int r = 0; r < 4; ++r) {
            int srow = q0 + r;
            float val = o[nt][r] / l_run[r];
            Xa[((size_t)b_ * S_LEN + srow) * D_MODEL + col] = f2b(val);
        }
    }
}

// ---------------------------------------------------------------------------
// Output projection: out = Xa @ wo^T + bo, fp32 row-major [B*S, D]
// ---------------------------------------------------------------------------
__global__ __launch_bounds__(256)
void gemm_out_kernel(const short* __restrict__ A, const short* __restrict__ W,
                     const float* __restrict__ bias, float* __restrict__ out)
{
    const int wave = threadIdx.x >> 6, lane = threadIdx.x & 63;
    const int quad = lane >> 4, l16 = lane & 15;
    const int mrow  = blockIdx.x * 64 + wave * 16 + l16;
    const int nbase = blockIdx.y * 64;

    floatx4 acc[4] = {{0,0,0,0},{0,0,0,0},{0,0,0,0},{0,0,0,0}};
    const short* Ap = A + (size_t)mrow * D_MODEL + quad * 8;

    for (int k0 = 0; k0 < D_MODEL; k0 += 32) {
        short8 a = *(const short8*)(Ap + k0);
#pragma unroll
        for (int nt = 0; nt < 4; ++nt) {
            short8 b = *(const short8*)(W + (size_t)(nbase + nt * 16 + l16) * D_MODEL + quad * 8 + k0);
            acc[nt] = __builtin_amdgcn_mfma_f32_16x16x32_bf16(a, b, acc[nt], 0, 0, 0);
        }
    }

    const int mtile = blockIdx.x * 64 + wave * 16;
#pragma unroll
    for (int nt = 0; nt < 4; ++nt) {
        int col = nbase + nt * 16 + l16;
        float bv_ = bias[col];
#pragma unroll
        for (int r = 0; r < 4; ++r) {
            int m = mtile + quad * 4 + r;
            out[(size_t)m * D_MODEL + col] = acc[nt][r] + bv_;
        }
    }
}

// ---------------------------------------------------------------------------
extern "C" void kernel_launch(void* const* d_in, const int* in_sizes, int n_in,
                              void* d_out, int out_size, void* d_ws, size_t ws_size,
                              hipStream_t stream)
{
    (void)in_sizes; (void)n_in; (void)out_size; (void)ws_size;
    const float* q  = (const float*)d_in[0];
    const float* k  = (const float*)d_in[1];
    const float* v  = (const float*)d_in[2];
    // d_in[3] = causal mask: implemented analytically, unused
    const float* wq = (const float*)d_in[4];
    const float* bq = (const float*)d_in[5];
    const float* wk = (const float*)d_in[6];
    const float* bk = (const float*)d_in[7];
    const float* wv = (const float*)d_in[8];
    const float* bv = (const float*)d_in[9];
    const float* wo = (const float*)d_in[10];
    const float* bo = (const float*)d_in[11];
    float* out = (float*)d_out;

    const size_t XE = (size_t)M_ROWS * D_MODEL;   // 4.19M elems
    const size_t WE = (size_t)D_MODEL * D_MODEL;  // 1.05M elems
    short* ws  = (short*)d_ws;
    short* xq_b = ws;              // XE   (reused as Xa after QKV GEMM)
    short* xk_b = xq_b + XE;       // XE
    short* xv_b = xk_b + XE;       // XE
    short* wq_b = xv_b + XE;       // WE
    short* wk_b = wq_b + WE;
    short* wv_b = wk_b + WE;
    short* wo_b = wv_b + WE;
    short* Qp   = wo_b + WE;       // XE  [B,H,S,DK]
    short* Kp   = Qp + XE;
    short* Vp   = Kp + XE;
    short* Xa   = xq_b;            // alias: x inputs dead after QKV GEMM

    dim3 blk(256);
    cvt_kernel<<<dim3((unsigned)(XE / 4 / 256)), blk, 0, stream>>>(q, xq_b, (int)XE);
    cvt_kernel<<<dim3((unsigned)(XE / 4 / 256)), blk, 0, stream>>>(k, xk_b, (int)XE);
    cvt_kernel<<<dim3((unsigned)(XE / 4 / 256)), blk, 0, stream>>>(v, xv_b, (int)XE);
    cvt_kernel<<<dim3((unsigned)(WE / 4 / 256)), blk, 0, stream>>>(wq, wq_b, (int)WE);
    cvt_kernel<<<dim3((unsigned)(WE / 4 / 256)), blk, 0, stream>>>(wk, wk_b, (int)WE);
    cvt_kernel<<<dim3((unsigned)(WE / 4 / 256)), blk, 0, stream>>>(wv, wv_b, (int)WE);
    cvt_kernel<<<dim3((unsigned)(WE / 4 / 256)), blk, 0, stream>>>(wo, wo_b, (int)WE);

    gemm_qkv_kernel<<<dim3(M_ROWS / 64, D_MODEL / 64, 3), blk, 0, stream>>>(
        xq_b, xk_b, xv_b, wq_b, wk_b, wv_b, bq, bk, bv, Qp, Kp, Vp);

    attn_kernel<<<dim3(S_LEN / 64, B_SZ * H_NUM), blk, 0, stream>>>(Qp, Kp, Vp, Xa);

    gemm_out_kernel<<<dim3(M_ROWS / 64, D_MODEL / 64), blk, 0, stream>>>(Xa, wo_b, bo, out);
}

// Round 3
// 322.046 us; speedup vs baseline: 1.8479x; 1.8479x over previous
//
#include <hip/hip_runtime.h>

#define B_SZ    2
#define S_LEN   2048
#define D_MODEL 1024
#define H_NUM   16
#define DK_H    64
#define M_ROWS  (B_SZ * S_LEN)   // 4096

typedef __attribute__((ext_vector_type(8))) short  short8;
typedef __attribute__((ext_vector_type(4))) short  short4v;
typedef __attribute__((ext_vector_type(4))) float  floatx4;

// fp32 -> bf16 round-to-nearest-even (finite inputs only)
__device__ __forceinline__ short f2b(float f) {
    union { float f; unsigned u; } x; x.f = f;
    unsigned u = x.u + 0x7fffu + ((x.u >> 16) & 1u);
    return (short)(u >> 16);
}

typedef __attribute__((address_space(1))) const unsigned int gu32;
typedef __attribute__((address_space(3))) unsigned int       lu32;
__device__ __forceinline__ void gload_lds16(const short* g, short* l) {
    // async global->LDS, 16B/lane; LDS dest must be wave_base + lane*16
    __builtin_amdgcn_global_load_lds((gu32*)g, (lu32*)l, 16, 0, 0);
}

// ---------------------------------------------------------------------------
// fp32 -> bf16 converts, merged: 3-tensor and 4-tensor variants
// ---------------------------------------------------------------------------
__global__ void cvt3_kernel(const float* __restrict__ i0, const float* __restrict__ i1,
                            const float* __restrict__ i2,
                            short* __restrict__ o0, short* __restrict__ o1, short* __restrict__ o2) {
    const float* in  = (blockIdx.y == 0) ? i0 : (blockIdx.y == 1) ? i1 : i2;
    short*       out = (blockIdx.y == 0) ? o0 : (blockIdx.y == 1) ? o1 : o2;
    int i = (blockIdx.x * 256 + threadIdx.x) * 4;
    float4 v = *(const float4*)(in + i);
    short4v r;
    r[0] = f2b(v.x); r[1] = f2b(v.y); r[2] = f2b(v.z); r[3] = f2b(v.w);
    *(short4v*)(out + i) = r;
}

__global__ void cvt4_kernel(const float* __restrict__ i0, const float* __restrict__ i1,
                            const float* __restrict__ i2, const float* __restrict__ i3,
                            short* __restrict__ o0, short* __restrict__ o1,
                            short* __restrict__ o2, short* __restrict__ o3) {
    const float* in  = (blockIdx.y == 0) ? i0 : (blockIdx.y == 1) ? i1 : (blockIdx.y == 2) ? i2 : i3;
    short*       out = (blockIdx.y == 0) ? o0 : (blockIdx.y == 1) ? o1 : (blockIdx.y == 2) ? o2 : o3;
    int i = (blockIdx.x * 256 + threadIdx.x) * 4;
    float4 v = *(const float4*)(in + i);
    short4v r;
    r[0] = f2b(v.x); r[1] = f2b(v.y); r[2] = f2b(v.z); r[3] = f2b(v.w);
    *(short4v*)(out + i) = r;
}

// ---------------------------------------------------------------------------
// Fused QKV projection, m97 structure: 128(M)x128(N) tile, BK=32,
// global_load_lds staging, swizzled LDS. blockIdx.y>>3 selects q/k/v.
// Q pre-scaled by 1/8. Q,K out as [B,H,S,DK]; V out TRANSPOSED [B,H,DK,S].
// LDS swizzle: chunk slot cs holds logical chunk cs ^ ((row>>1)&3).
// ---------------------------------------------------------------------------
__global__ __launch_bounds__(256)
void gemm_qkv_kernel(const short* __restrict__ xq, const short* __restrict__ xk,
                     const short* __restrict__ xv,
                     const short* __restrict__ wq, const short* __restrict__ wk,
                     const short* __restrict__ wv,
                     const float* __restrict__ bq, const float* __restrict__ bk,
                     const float* __restrict__ bv,
                     short* __restrict__ Qp, short* __restrict__ Kp, short* __restrict__ Vt)
{
    __shared__ short sa[128 * 32];
    __shared__ short sb[128 * 32];

    const int which = blockIdx.y >> 3;
    const short* A    = (which == 0) ? xq : (which == 1) ? xk : xv;
    const short* W    = (which == 0) ? wq : (which == 1) ? wk : wv;
    const float* bias = (which == 0) ? bq : (which == 1) ? bk : bv;
    const float scale = (which == 0) ? 0.125f : 1.0f;

    const int nb = (blockIdx.y & 7) * 128;
    const int m0 = blockIdx.x * 128;
    const int t = threadIdx.x, wave = t >> 6, lane = t & 63;
    const int quad = lane >> 4, l16 = lane & 15;
    const int wm = (wave & 1) * 64, wn = (wave >> 1) * 64;

    // staging: thread t -> tile row r0=t>>2 (and r0+64), stored chunk slot cs=t&3
    const int r0 = t >> 2, cs = t & 3;
    const int c0 = cs ^ ((r0 >> 1) & 3);            // logical chunk held in slot cs
    const short* Ab0 = A + (size_t)(m0 + r0) * D_MODEL + c0 * 8;
    const short* Ab1 = Ab0 + (size_t)64 * D_MODEL;
    const short* Bb0 = W + (size_t)(nb + r0) * D_MODEL + c0 * 8;
    const short* Bb1 = Bb0 + (size_t)64 * D_MODEL;
    short* sa0 = sa + t * 8;  short* sa1 = sa + 2048 + t * 8;
    short* sb0 = sb + t * 8;  short* sb1 = sb + 2048 + t * 8;

    // fragment LDS offsets (invariant across K)
    int a_off[4], b_off[4];
#pragma unroll
    for (int i = 0; i < 4; ++i) {
        int ar = wm + i * 16 + l16;
        a_off[i] = ar * 32 + ((quad ^ ((ar >> 1) & 3)) * 8);
        int br = wn + i * 16 + l16;
        b_off[i] = br * 32 + ((quad ^ ((br >> 1) & 3)) * 8);
    }

    floatx4 acc[4][4] = {};
    for (int k0 = 0; k0 < D_MODEL; k0 += 32) {
        __syncthreads();
        gload_lds16(Ab0 + k0, sa0);
        gload_lds16(Ab1 + k0, sa1);
        gload_lds16(Bb0 + k0, sb0);
        gload_lds16(Bb1 + k0, sb1);
        __syncthreads();
        short8 af[4], bf[4];
#pragma unroll
        for (int i = 0; i < 4; ++i) af[i] = *(const short8*)(sa + a_off[i]);
#pragma unroll
        for (int i = 0; i < 4; ++i) bf[i] = *(const short8*)(sb + b_off[i]);
#pragma unroll
        for (int mt = 0; mt < 4; ++mt)
#pragma unroll
            for (int nt = 0; nt < 4; ++nt)
                acc[mt][nt] = __builtin_amdgcn_mfma_f32_16x16x32_bf16(af[mt], bf[nt], acc[mt][nt], 0, 0, 0);
    }

    // epilogue
#pragma unroll
    for (int nt = 0; nt < 4; ++nt) {
        int ncol = nb + wn + nt * 16 + l16;
        int h = ncol >> 6, dk = ncol & 63;
        float bv_ = bias[ncol];
#pragma unroll
        for (int mt = 0; mt < 4; ++mt) {
            int mrow0 = m0 + wm + mt * 16 + quad * 4;
            int bb = mrow0 >> 11, s0 = mrow0 & (S_LEN - 1);
            if (which < 2) {
                short* Out = (which == 0) ? Qp : Kp;
#pragma unroll
                for (int r = 0; r < 4; ++r) {
                    float v = (acc[mt][nt][r] + bv_) * scale;
                    Out[(((size_t)bb * H_NUM + h) * S_LEN + (s0 + r)) * DK_H + dk] = f2b(v);
                }
            } else {
                short4v pk;
#pragma unroll
                for (int r = 0; r < 4; ++r) pk[r] = f2b(acc[mt][nt][r] + bv_);
                *(short4v*)(&Vt[(((size_t)bb * H_NUM + h) * DK_H + dk) * S_LEN + s0]) = pk;
            }
        }
    }
}

// ---------------------------------------------------------------------------
// Flash-style causal attention. Grid: (S/64 q-tiles, B*H). 4 waves/block,
// each wave owns 16 q-rows. K tile [key][dk], V^T tile [dk][key], vector
// staged (V pre-transposed in global). 2 barriers/k-tile.
// ---------------------------------------------------------------------------
__global__ __launch_bounds__(256)
void attn_kernel(const short* __restrict__ Qp, const short* __restrict__ Kp,
                 const short* __restrict__ Vt, short* __restrict__ Xa)
{
    __shared__ short kt[64][72];      // [key][dk]
    __shared__ short vt[64][72];      // [dk][key]
    __shared__ short pl[4][16][72];   // per-wave P round-trip (wave-private)

    const int bh = blockIdx.y;
    const int qt = blockIdx.x;
    const int t = threadIdx.x, wave = t >> 6, lane = t & 63;
    const int quad = lane >> 4, l16 = lane & 15;

    const short* Qb  = Qp + (size_t)bh * S_LEN * DK_H;
    const short* Kb  = Kp + (size_t)bh * S_LEN * DK_H;
    const short* Vtb = Vt + (size_t)bh * DK_H * S_LEN;   // [64][2048]

    const int qrow_f = qt * 64 + wave * 16 + l16;
    short8 qf0 = *(const short8*)(Qb + (size_t)qrow_f * DK_H + quad * 8);
    short8 qf1 = *(const short8*)(Qb + (size_t)qrow_f * DK_H + 32 + quad * 8);

    floatx4 o[4] = {};
    float m_run[4] = {-1e30f, -1e30f, -1e30f, -1e30f};
    float l_run[4] = {0.f, 0.f, 0.f, 0.f};
    const int q0 = qt * 64 + wave * 16 + quad * 4;

    for (int kti = 0; kti <= qt; ++kti) {
        const int kbase = kti * 64;
        __syncthreads();
        // K tile: 64 keys x 64 dk = 512 chunks of 8 shorts (8 chunks/row)
        {
            const short* src = Kb + (size_t)kbase * DK_H;
#pragma unroll
            for (int it = 0; it < 2; ++it) {
                int f = it * 256 + t;
                *(short8*)(&kt[f >> 3][(f & 7) * 8]) = *(const short8*)(src + f * 8);
            }
        }
        // V^T tile: 64 dk-rows x 64 keys (8 chunks/row)
        {
#pragma unroll
            for (int it = 0; it < 2; ++it) {
                int f = it * 256 + t;
                int row = f >> 3, ch = (f & 7) * 8;
                *(short8*)(&vt[row][ch]) = *(const short8*)(Vtb + (size_t)row * S_LEN + kbase + ch);
            }
        }
        __syncthreads();

        // S = Q K^T (Q pre-scaled)
        floatx4 sc4[4] = {};
#pragma unroll
        for (int nt = 0; nt < 4; ++nt) {
            short8 b0 = *(const short8*)(&kt[nt * 16 + l16][quad * 8]);
            sc4[nt] = __builtin_amdgcn_mfma_f32_16x16x32_bf16(qf0, b0, sc4[nt], 0, 0, 0);
            short8 b1 = *(const short8*)(&kt[nt * 16 + l16][32 + quad * 8]);
            sc4[nt] = __builtin_amdgcn_mfma_f32_16x16x32_bf16(qf1, b1, sc4[nt], 0, 0, 0);
        }

        if (kti == qt) {  // causal mask on diagonal tile
#pragma unroll
            for (int nt = 0; nt < 4; ++nt) {
                int key = kbase + nt * 16 + l16;
#pragma unroll
                for (int r = 0; r < 4; ++r)
                    if (key > q0 + r) sc4[nt][r] = -1e30f;
            }
        }

        // online softmax (row r lives across the 16-lane group)
        float alpha[4];
#pragma unroll
        for (int r = 0; r < 4; ++r) {
            float mx = fmaxf(fmaxf(sc4[0][r], sc4[1][r]), fmaxf(sc4[2][r], sc4[3][r]));
            mx = fmaxf(mx, __shfl_xor(mx, 1));
            mx = fmaxf(mx, __shfl_xor(mx, 2));
            mx = fmaxf(mx, __shfl_xor(mx, 4));
            mx = fmaxf(mx, __shfl_xor(mx, 8));
            float mnew = fmaxf(m_run[r], mx);
            float a = __expf(m_run[r] - mnew);
            float sum = 0.f;
#pragma unroll
            for (int nt = 0; nt < 4; ++nt) {
                float p = __expf(sc4[nt][r] - mnew);
                sc4[nt][r] = p;
                sum += p;
            }
            sum += __shfl_xor(sum, 1);
            sum += __shfl_xor(sum, 2);
            sum += __shfl_xor(sum, 4);
            sum += __shfl_xor(sum, 8);
            l_run[r] = l_run[r] * a + sum;
            m_run[r] = mnew;
            alpha[r] = a;
        }

        // P: C-layout regs -> LDS -> A-layout (wave-private; DS in-order per wave)
#pragma unroll
        for (int nt = 0; nt < 4; ++nt)
#pragma unroll
            for (int r = 0; r < 4; ++r)
                pl[wave][quad * 4 + r][nt * 16 + l16] = f2b(sc4[nt][r]);

#pragma unroll
        for (int nt = 0; nt < 4; ++nt)
#pragma unroll
            for (int r = 0; r < 4; ++r) o[nt][r] *= alpha[r];

#pragma unroll
        for (int ks = 0; ks < 2; ++ks) {
            short8 a = *(const short8*)(&pl[wave][l16][ks * 32 + quad * 8]);
#pragma unroll
            for (int nt = 0; nt < 4; ++nt) {
                short8 b = *(const short8*)(&vt[nt * 16 + l16][ks * 32 + quad * 8]);
                o[nt] = __builtin_amdgcn_mfma_f32_16x16x32_bf16(a, b, o[nt], 0, 0, 0);
            }
        }
    }

    // epilogue -> Xa [B,S,D] bf16
    const int b_ = bh >> 4, h = bh & 15;
#pragma unroll
    for (int nt = 0; nt < 4; ++nt) {
        int col = h * 64 + nt * 16 + l16;
#pragma unroll
        for (int r = 0; r < 4; ++r) {
            int srow = q0 + r;
            float val = o[nt][r] / l_run[r];
            Xa[((size_t)b_ * S_LEN + srow) * D_MODEL + col] = f2b(val);
        }
    }
}

// ---------------------------------------------------------------------------
// Output projection, m97 structure: out = Xa @ wo^T + bo (fp32 out)
// ---------------------------------------------------------------------------
__global__ __launch_bounds__(256)
void gemm_out_kernel(const short* __restrict__ A, const short* __restrict__ W,
                     const float* __restrict__ bias, float* __restrict__ out)
{
    __shared__ short sa[128 * 32];
    __shared__ short sb[128 * 32];

    const int nb = blockIdx.y * 128;
    const int m0 = blockIdx.x * 128;
    const int t = threadIdx.x, wave = t >> 6, lane = t & 63;
    const int quad = lane >> 4, l16 = lane & 15;
    const int wm = (wave & 1) * 64, wn = (wave >> 1) * 64;

    const int r0 = t >> 2, cs = t & 3;
    const int c0 = cs ^ ((r0 >> 1) & 3);
    const short* Ab0 = A + (size_t)(m0 + r0) * D_MODEL + c0 * 8;
    const short* Ab1 = Ab0 + (size_t)64 * D_MODEL;
    const short* Bb0 = W + (size_t)(nb + r0) * D_MODEL + c0 * 8;
    const short* Bb1 = Bb0 + (size_t)64 * D_MODEL;
    short* sa0 = sa + t * 8;  short* sa1 = sa + 2048 + t * 8;
    short* sb0 = sb + t * 8;  short* sb1 = sb + 2048 + t * 8;

    int a_off[4], b_off[4];
#pragma unroll
    for (int i = 0; i < 4; ++i) {
        int ar = wm + i * 16 + l16;
        a_off[i] = ar * 32 + ((quad ^ ((ar >> 1) & 3)) * 8);
        int br = wn + i * 16 + l16;
        b_off[i] = br * 32 + ((quad ^ ((br >> 1) & 3)) * 8);
    }

    floatx4 acc[4][4] = {};
    for (int k0 = 0; k0 < D_MODEL; k0 += 32) {
        __syncthreads();
        gload_lds16(Ab0 + k0, sa0);
        gload_lds16(Ab1 + k0, sa1);
        gload_lds16(Bb0 + k0, sb1 - 2048);   // sb0
        gload_lds16(Bb1 + k0, sb1);
        __syncthreads();
        short8 af[4], bf[4];
#pragma unroll
        for (int i = 0; i < 4; ++i) af[i] = *(const short8*)(sa + a_off[i]);
#pragma unroll
        for (int i = 0; i < 4; ++i) bf[i] = *(const short8*)(sb + b_off[i]);
#pragma unroll
        for (int mt = 0; mt < 4; ++mt)
#pragma unroll
            for (int nt = 0; nt < 4; ++nt)
                acc[mt][nt] = __builtin_amdgcn_mfma_f32_16x16x32_bf16(af[mt], bf[nt], acc[mt][nt], 0, 0, 0);
    }

#pragma unroll
    for (int nt = 0; nt < 4; ++nt) {
        int ncol = nb + wn + nt * 16 + l16;
        float bv_ = bias[ncol];
#pragma unroll
        for (int mt = 0; mt < 4; ++mt) {
            int mrow0 = m0 + wm + mt * 16 + quad * 4;
#pragma unroll
            for (int r = 0; r < 4; ++r)
                out[(size_t)(mrow0 + r) * D_MODEL + ncol] = acc[mt][nt][r] + bv_;
        }
    }
}

// ---------------------------------------------------------------------------
extern "C" void kernel_launch(void* const* d_in, const int* in_sizes, int n_in,
                              void* d_out, int out_size, void* d_ws, size_t ws_size,
                              hipStream_t stream)
{
    (void)in_sizes; (void)n_in; (void)out_size; (void)ws_size;
    const float* q  = (const float*)d_in[0];
    const float* k  = (const float*)d_in[1];
    const float* v  = (const float*)d_in[2];
    // d_in[3] = causal mask: analytic, unused
    const float* wq = (const float*)d_in[4];
    const float* bq = (const float*)d_in[5];
    const float* wk = (const float*)d_in[6];
    const float* bk = (const float*)d_in[7];
    const float* wv = (const float*)d_in[8];
    const float* bv = (const float*)d_in[9];
    const float* wo = (const float*)d_in[10];
    const float* bo = (const float*)d_in[11];
    float* out = (float*)d_out;

    const size_t XE = (size_t)M_ROWS * D_MODEL;
    const size_t WE = (size_t)D_MODEL * D_MODEL;
    short* ws_  = (short*)d_ws;
    short* xq_b = ws_;             // XE (reused as Xa after QKV GEMM)
    short* xk_b = xq_b + XE;
    short* xv_b = xk_b + XE;
    short* wq_b = xv_b + XE;
    short* wk_b = wq_b + WE;
    short* wv_b = wk_b + WE;
    short* wo_b = wv_b + WE;
    short* Qp   = wo_b + WE;       // [B,H,S,DK]
    short* Kp   = Qp + XE;
    short* Vt   = Kp + XE;         // [B,H,DK,S]
    short* Xa   = xq_b;

    dim3 blk(256);
    cvt3_kernel<<<dim3((unsigned)(XE / 1024), 3), blk, 0, stream>>>(q, k, v, xq_b, xk_b, xv_b);
    cvt4_kernel<<<dim3((unsigned)(WE / 1024), 4), blk, 0, stream>>>(wq, wk, wv, wo, wq_b, wk_b, wv_b, wo_b);

    gemm_qkv_kernel<<<dim3(M_ROWS / 128, 24), blk, 0, stream>>>(
        xq_b, xk_b, xv_b, wq_b, wk_b, wv_b, bq, bk, bv, Qp, Kp, Vt);

    attn_kernel<<<dim3(S_LEN / 64, B_SZ * H_NUM), blk, 0, stream>>>(Qp, Kp, Vt, Xa);

    gemm_out_kernel<<<dim3(M_ROWS / 128, D_MODEL / 128), blk, 0, stream>>>(Xa, wo_b, bo, out);
}

// Round 4
// 317.679 us; speedup vs baseline: 1.8733x; 1.0137x over previous
//
#include <hip/hip_runtime.h>

#define B_SZ    2
#define S_LEN   2048
#define D_MODEL 1024
#define H_NUM   16
#define DK_H    64
#define M_ROWS  (B_SZ * S_LEN)   // 4096

typedef __attribute__((ext_vector_type(8))) short  short8;
typedef __attribute__((ext_vector_type(4))) short  short4v;
typedef __attribute__((ext_vector_type(4))) float  floatx4;

// fp32 -> bf16 round-to-nearest-even (finite inputs only)
__device__ __forceinline__ short f2b(float f) {
    union { float f; unsigned u; } x; x.f = f;
    unsigned u = x.u + 0x7fffu + ((x.u >> 16) & 1u);
    return (short)(u >> 16);
}

typedef __attribute__((address_space(1))) const unsigned int gu32;
typedef __attribute__((address_space(3))) unsigned int       lu32;
__device__ __forceinline__ void gload_lds16(const short* g, short* l) {
    __builtin_amdgcn_global_load_lds((gu32*)g, (lu32*)l, 16, 0, 0);
}

// log2(e)/sqrt(DK): folded into Q so softmax runs in exp2 domain
#define QSCALE 0.18033688011112042f

// ---------------------------------------------------------------------------
// fp32 -> bf16 converts, merged
// ---------------------------------------------------------------------------
__global__ void cvt3_kernel(const float* __restrict__ i0, const float* __restrict__ i1,
                            const float* __restrict__ i2,
                            short* __restrict__ o0, short* __restrict__ o1, short* __restrict__ o2) {
    const float* in  = (blockIdx.y == 0) ? i0 : (blockIdx.y == 1) ? i1 : i2;
    short*       out = (blockIdx.y == 0) ? o0 : (blockIdx.y == 1) ? o1 : o2;
    int i = (blockIdx.x * 256 + threadIdx.x) * 4;
    float4 v = *(const float4*)(in + i);
    short4v r;
    r[0] = f2b(v.x); r[1] = f2b(v.y); r[2] = f2b(v.z); r[3] = f2b(v.w);
    *(short4v*)(out + i) = r;
}

__global__ void cvt4_kernel(const float* __restrict__ i0, const float* __restrict__ i1,
                            const float* __restrict__ i2, const float* __restrict__ i3,
                            short* __restrict__ o0, short* __restrict__ o1,
                            short* __restrict__ o2, short* __restrict__ o3) {
    const float* in  = (blockIdx.y == 0) ? i0 : (blockIdx.y == 1) ? i1 : (blockIdx.y == 2) ? i2 : i3;
    short*       out = (blockIdx.y == 0) ? o0 : (blockIdx.y == 1) ? o1 : (blockIdx.y == 2) ? o2 : o3;
    int i = (blockIdx.x * 256 + threadIdx.x) * 4;
    float4 v = *(const float4*)(in + i);
    short4v r;
    r[0] = f2b(v.x); r[1] = f2b(v.y); r[2] = f2b(v.z); r[3] = f2b(v.w);
    *(short4v*)(out + i) = r;
}

// ---------------------------------------------------------------------------
// Fused QKV projection (m97 structure). Q scaled by log2e/8 (exp2-domain
// softmax). Q,K out [B,H,S,DK]; V out transposed [B,H,DK,S].
// ---------------------------------------------------------------------------
__global__ __launch_bounds__(256)
void gemm_qkv_kernel(const short* __restrict__ xq, const short* __restrict__ xk,
                     const short* __restrict__ xv,
                     const short* __restrict__ wq, const short* __restrict__ wk,
                     const short* __restrict__ wv,
                     const float* __restrict__ bq, const float* __restrict__ bk,
                     const float* __restrict__ bv,
                     short* __restrict__ Qp, short* __restrict__ Kp, short* __restrict__ Vt)
{
    __shared__ short sa[128 * 32];
    __shared__ short sb[128 * 32];

    const int which = blockIdx.y >> 3;
    const short* A    = (which == 0) ? xq : (which == 1) ? xk : xv;
    const short* W    = (which == 0) ? wq : (which == 1) ? wk : wv;
    const float* bias = (which == 0) ? bq : (which == 1) ? bk : bv;
    const float scale = (which == 0) ? QSCALE : 1.0f;

    const int nb = (blockIdx.y & 7) * 128;
    const int m0 = blockIdx.x * 128;
    const int t = threadIdx.x, wave = t >> 6, lane = t & 63;
    const int quad = lane >> 4, l16 = lane & 15;
    const int wm = (wave & 1) * 64, wn = (wave >> 1) * 64;

    const int r0 = t >> 2, cs = t & 3;
    const int c0 = cs ^ ((r0 >> 1) & 3);
    const short* Ab0 = A + (size_t)(m0 + r0) * D_MODEL + c0 * 8;
    const short* Ab1 = Ab0 + (size_t)64 * D_MODEL;
    const short* Bb0 = W + (size_t)(nb + r0) * D_MODEL + c0 * 8;
    const short* Bb1 = Bb0 + (size_t)64 * D_MODEL;
    short* sa0 = sa + t * 8;  short* sa1 = sa + 2048 + t * 8;
    short* sb0 = sb + t * 8;  short* sb1 = sb + 2048 + t * 8;

    int a_off[4], b_off[4];
#pragma unroll
    for (int i = 0; i < 4; ++i) {
        int ar = wm + i * 16 + l16;
        a_off[i] = ar * 32 + ((quad ^ ((ar >> 1) & 3)) * 8);
        int br = wn + i * 16 + l16;
        b_off[i] = br * 32 + ((quad ^ ((br >> 1) & 3)) * 8);
    }

    floatx4 acc[4][4] = {};
    for (int k0 = 0; k0 < D_MODEL; k0 += 32) {
        __syncthreads();
        gload_lds16(Ab0 + k0, sa0);
        gload_lds16(Ab1 + k0, sa1);
        gload_lds16(Bb0 + k0, sb0);
        gload_lds16(Bb1 + k0, sb1);
        __syncthreads();
        short8 af[4], bf[4];
#pragma unroll
        for (int i = 0; i < 4; ++i) af[i] = *(const short8*)(sa + a_off[i]);
#pragma unroll
        for (int i = 0; i < 4; ++i) bf[i] = *(const short8*)(sb + b_off[i]);
#pragma unroll
        for (int mt = 0; mt < 4; ++mt)
#pragma unroll
            for (int nt = 0; nt < 4; ++nt)
                acc[mt][nt] = __builtin_amdgcn_mfma_f32_16x16x32_bf16(af[mt], bf[nt], acc[mt][nt], 0, 0, 0);
    }

#pragma unroll
    for (int nt = 0; nt < 4; ++nt) {
        int ncol = nb + wn + nt * 16 + l16;
        int h = ncol >> 6, dk = ncol & 63;
        float bv_ = bias[ncol];
#pragma unroll
        for (int mt = 0; mt < 4; ++mt) {
            int mrow0 = m0 + wm + mt * 16 + quad * 4;
            int bb = mrow0 >> 11, s0 = mrow0 & (S_LEN - 1);
            if (which < 2) {
                short* Out = (which == 0) ? Qp : Kp;
#pragma unroll
                for (int r = 0; r < 4; ++r) {
                    float v = (acc[mt][nt][r] + bv_) * scale;
                    Out[(((size_t)bb * H_NUM + h) * S_LEN + (s0 + r)) * DK_H + dk] = f2b(v);
                }
            } else {
                short4v pk;
#pragma unroll
                for (int r = 0; r < 4; ++r) pk[r] = f2b(acc[mt][nt][r] + bv_);
                *(short4v*)(&Vt[(((size_t)bb * H_NUM + h) * DK_H + dk) * S_LEN + s0]) = pk;
            }
        }
    }
}

// ---------------------------------------------------------------------------
// Barrier-free flash attention. Grid (16 qblk, 32 bh), 4 waves/block.
// Wave = 32 q-rows (2 fragment groups sharing K/V b-frags read DIRECT from
// global (L2)). Running row-sum l computed by an extra MFMA against a
// constant ones-column B-fragment. No __syncthreads anywhere.
// ---------------------------------------------------------------------------
__global__ __launch_bounds__(256)
void attn_kernel(const short* __restrict__ Qp, const short* __restrict__ Kp,
                 const short* __restrict__ Vt, short* __restrict__ Xa)
{
    __shared__ short pl[4][16 * 72];   // per-wave P round-trip

    const int bh = blockIdx.y;
    const int qblk = 15 - blockIdx.x;            // LPT: heavy blocks first
    const int t = threadIdx.x, wave = t >> 6, lane = t & 63;
    const int quad = lane >> 4, l16 = lane & 15;

    const short* Qb  = Qp + (size_t)bh * S_LEN * DK_H;
    const short* Kb  = Kp + (size_t)bh * S_LEN * DK_H;
    const short* Vtb = Vt + (size_t)bh * DK_H * S_LEN;   // [64][2048]

    const int q0 = qblk * 128 + wave * 32;       // this wave's 32 q-rows
    const int ktimax = (q0 + 31) >> 6;

    // Q a-frags: [group][k-chunk]
    short8 qf[2][2];
#pragma unroll
    for (int g = 0; g < 2; ++g)
#pragma unroll
        for (int ks = 0; ks < 2; ++ks)
            qf[g][ks] = *(const short8*)(Qb + (size_t)(q0 + g * 16 + l16) * DK_H + ks * 32 + quad * 8);

    // constant ones-column B-frag: B[n=l16][k]=1 iff n==0 -> C col 0 = row sum
    short8 bl = {};
    if (l16 == 0) {
#pragma unroll
        for (int j = 0; j < 8; ++j) bl[j] = (short)0x3F80;   // bf16 1.0
    }

    floatx4 o[2][4] = {};
    floatx4 ol[2] = {};
    float m_run[2][4] = {{-1e30f,-1e30f,-1e30f,-1e30f},{-1e30f,-1e30f,-1e30f,-1e30f}};

    short* plw = &pl[wave][0];

    for (int kti = 0; kti <= ktimax; ++kti) {
        const int kbase = kti * 64;

        // K b-frags (direct from global/L2), shared by both groups
        short8 bk[4][2];
#pragma unroll
        for (int nt = 0; nt < 4; ++nt)
#pragma unroll
            for (int ks = 0; ks < 2; ++ks)
                bk[nt][ks] = *(const short8*)(Kb + (size_t)(kbase + nt * 16 + l16) * DK_H + ks * 32 + quad * 8);

        // S = Q K^T for both groups
        floatx4 sc[2][4] = {};
#pragma unroll
        for (int g = 0; g < 2; ++g)
#pragma unroll
            for (int nt = 0; nt < 4; ++nt)
#pragma unroll
                for (int ks = 0; ks < 2; ++ks)
                    sc[g][nt] = __builtin_amdgcn_mfma_f32_16x16x32_bf16(qf[g][ks], bk[nt][ks], sc[g][nt], 0, 0, 0);

        // V^T b-frags (direct from global/L2), shared by both groups
        short8 bv[4][2];
#pragma unroll
        for (int nt = 0; nt < 4; ++nt)
#pragma unroll
            for (int ks = 0; ks < 2; ++ks)
                bv[nt][ks] = *(const short8*)(Vtb + (size_t)(nt * 16 + l16) * S_LEN + kbase + ks * 32 + quad * 8);

        const bool diag = (kti == ktimax);

#pragma unroll
        for (int g = 0; g < 2; ++g) {
            const int qg = q0 + g * 16 + quad * 4;
            if (diag) {
#pragma unroll
                for (int nt = 0; nt < 4; ++nt) {
                    int key = kbase + nt * 16 + l16;
#pragma unroll
                    for (int r = 0; r < 4; ++r)
                        if (key > qg + r) sc[g][nt][r] = -1e30f;
                }
            }

            // online softmax: max via shuffles; sum via MFMA ones-column
            float alpha[4];
#pragma unroll
            for (int r = 0; r < 4; ++r) {
                float mx = fmaxf(fmaxf(sc[g][0][r], sc[g][1][r]), fmaxf(sc[g][2][r], sc[g][3][r]));
                mx = fmaxf(mx, __shfl_xor(mx, 1));
                mx = fmaxf(mx, __shfl_xor(mx, 2));
                mx = fmaxf(mx, __shfl_xor(mx, 4));
                mx = fmaxf(mx, __shfl_xor(mx, 8));
                float mnew = fmaxf(m_run[g][r], mx);
                alpha[r] = exp2f(m_run[g][r] - mnew);
                m_run[g][r] = mnew;
#pragma unroll
                for (int nt = 0; nt < 4; ++nt)
                    sc[g][nt][r] = exp2f(sc[g][nt][r] - mnew);
            }

            // P: C-layout -> LDS -> A-layout (wave-private; DS in-order per wave)
#pragma unroll
            for (int nt = 0; nt < 4; ++nt)
#pragma unroll
                for (int r = 0; r < 4; ++r)
                    plw[(quad * 4 + r) * 72 + nt * 16 + l16] = f2b(sc[g][nt][r]);

            // rescale accumulators
#pragma unroll
            for (int nt = 0; nt < 4; ++nt)
#pragma unroll
                for (int r = 0; r < 4; ++r) o[g][nt][r] *= alpha[r];
#pragma unroll
            for (int r = 0; r < 4; ++r) ol[g][r] *= alpha[r];

            short8 ap0 = *(const short8*)(plw + l16 * 72 + quad * 8);
            short8 ap1 = *(const short8*)(plw + l16 * 72 + 32 + quad * 8);

#pragma unroll
            for (int nt = 0; nt < 4; ++nt) {
                o[g][nt] = __builtin_amdgcn_mfma_f32_16x16x32_bf16(ap0, bv[nt][0], o[g][nt], 0, 0, 0);
                o[g][nt] = __builtin_amdgcn_mfma_f32_16x16x32_bf16(ap1, bv[nt][1], o[g][nt], 0, 0, 0);
            }
            ol[g] = __builtin_amdgcn_mfma_f32_16x16x32_bf16(ap0, bl, ol[g], 0, 0, 0);
            ol[g] = __builtin_amdgcn_mfma_f32_16x16x32_bf16(ap1, bl, ol[g], 0, 0, 0);
        }
    }

    // epilogue -> Xa [B,S,D] bf16. l for row quad*4+r lives in lane quad*16.
    const int b_ = bh >> 4, h = bh & 15;
#pragma unroll
    for (int g = 0; g < 2; ++g) {
#pragma unroll
        for (int r = 0; r < 4; ++r) {
            float lsum = __shfl(ol[g][r], (lane & 48));
            float rinv = 1.0f / lsum;
            int srow = q0 + g * 16 + quad * 4 + r;
#pragma unroll
            for (int nt = 0; nt < 4; ++nt) {
                int col = h * 64 + nt * 16 + l16;
                Xa[((size_t)b_ * S_LEN + srow) * D_MODEL + col] = f2b(o[g][nt][r] * rinv);
            }
        }
    }
}

// ---------------------------------------------------------------------------
// Output projection (m97 structure): out = Xa @ wo^T + bo (fp32)
// ---------------------------------------------------------------------------
__global__ __launch_bounds__(256)
void gemm_out_kernel(const short* __restrict__ A, const short* __restrict__ W,
                     const float* __restrict__ bias, float* __restrict__ out)
{
    __shared__ short sa[128 * 32];
    __shared__ short sb[128 * 32];

    const int nb = blockIdx.y * 128;
    const int m0 = blockIdx.x * 128;
    const int t = threadIdx.x, wave = t >> 6, lane = t & 63;
    const int quad = lane >> 4, l16 = lane & 15;
    const int wm = (wave & 1) * 64, wn = (wave >> 1) * 64;

    const int r0 = t >> 2, cs = t & 3;
    const int c0 = cs ^ ((r0 >> 1) & 3);
    const short* Ab0 = A + (size_t)(m0 + r0) * D_MODEL + c0 * 8;
    const short* Ab1 = Ab0 + (size_t)64 * D_MODEL;
    const short* Bb0 = W + (size_t)(nb + r0) * D_MODEL + c0 * 8;
    const short* Bb1 = Bb0 + (size_t)64 * D_MODEL;
    short* sa0 = sa + t * 8;  short* sa1 = sa + 2048 + t * 8;
    short* sb0 = sb + t * 8;  short* sb1 = sb + 2048 + t * 8;

    int a_off[4], b_off[4];
#pragma unroll
    for (int i = 0; i < 4; ++i) {
        int ar = wm + i * 16 + l16;
        a_off[i] = ar * 32 + ((quad ^ ((ar >> 1) & 3)) * 8);
        int br = wn + i * 16 + l16;
        b_off[i] = br * 32 + ((quad ^ ((br >> 1) & 3)) * 8);
    }

    floatx4 acc[4][4] = {};
    for (int k0 = 0; k0 < D_MODEL; k0 += 32) {
        __syncthreads();
        gload_lds16(Ab0 + k0, sa0);
        gload_lds16(Ab1 + k0, sa1);
        gload_lds16(Bb0 + k0, sb0);
        gload_lds16(Bb1 + k0, sb1);
        __syncthreads();
        short8 af[4], bf[4];
#pragma unroll
        for (int i = 0; i < 4; ++i) af[i] = *(const short8*)(sa + a_off[i]);
#pragma unroll
        for (int i = 0; i < 4; ++i) bf[i] = *(const short8*)(sb + b_off[i]);
#pragma unroll
        for (int mt = 0; mt < 4; ++mt)
#pragma unroll
            for (int nt = 0; nt < 4; ++nt)
                acc[mt][nt] = __builtin_amdgcn_mfma_f32_16x16x32_bf16(af[mt], bf[nt], acc[mt][nt], 0, 0, 0);
    }

#pragma unroll
    for (int nt = 0; nt < 4; ++nt) {
        int ncol = nb + wn + nt * 16 + l16;
        float bv_ = bias[ncol];
#pragma unroll
        for (int mt = 0; mt < 4; ++mt) {
            int mrow0 = m0 + wm + mt * 16 + quad * 4;
#pragma unroll
            for (int r = 0; r < 4; ++r)
                out[(size_t)(mrow0 + r) * D_MODEL + ncol] = acc[mt][nt][r] + bv_;
        }
    }
}

// ---------------------------------------------------------------------------
extern "C" void kernel_launch(void* const* d_in, const int* in_sizes, int n_in,
                              void* d_out, int out_size, void* d_ws, size_t ws_size,
                              hipStream_t stream)
{
    (void)in_sizes; (void)n_in; (void)out_size; (void)ws_size;
    const float* q  = (const float*)d_in[0];
    const float* k  = (const float*)d_in[1];
    const float* v  = (const float*)d_in[2];
    // d_in[3] = causal mask: analytic, unused
    const float* wq = (const float*)d_in[4];
    const float* bq = (const float*)d_in[5];
    const float* wk = (const float*)d_in[6];
    const float* bk = (const float*)d_in[7];
    const float* wv = (const float*)d_in[8];
    const float* bv = (const float*)d_in[9];
    const float* wo = (const float*)d_in[10];
    const float* bo = (const float*)d_in[11];
    float* out = (float*)d_out;

    const size_t XE = (size_t)M_ROWS * D_MODEL;
    const size_t WE = (size_t)D_MODEL * D_MODEL;
    short* ws_  = (short*)d_ws;
    short* xq_b = ws_;             // XE (reused as Xa after QKV GEMM)
    short* xk_b = xq_b + XE;
    short* xv_b = xk_b + XE;
    short* wq_b = xv_b + XE;
    short* wk_b = wq_b + WE;
    short* wv_b = wk_b + WE;
    short* wo_b = wv_b + WE;
    short* Qp   = wo_b + WE;       // [B,H,S,DK]
    short* Kp   = Qp + XE;
    short* Vt   = Kp + XE;         // [B,H,DK,S]
    short* Xa   = xq_b;

    dim3 blk(256);
    cvt3_kernel<<<dim3((unsigned)(XE / 1024), 3), blk, 0, stream>>>(q, k, v, xq_b, xk_b, xv_b);
    cvt4_kernel<<<dim3((unsigned)(WE / 1024), 4), blk, 0, stream>>>(wq, wk, wv, wo, wq_b, wk_b, wv_b, wo_b);

    gemm_qkv_kernel<<<dim3(M_ROWS / 128, 24), blk, 0, stream>>>(
        xq_b, xk_b, xv_b, wq_b, wk_b, wv_b, bq, bk, bv, Qp, Kp, Vt);

    attn_kernel<<<dim3(16, B_SZ * H_NUM), blk, 0, stream>>>(Qp, Kp, Vt, Xa);

    gemm_out_kernel<<<dim3(M_ROWS / 128, D_MODEL / 128), blk, 0, stream>>>(Xa, wo_b, bo, out);
}